// Round 10
// baseline (622.221 us; speedup 1.0000x reference)
//
#include <hip/hip_runtime.h>
#include <cstdint>
#include <cstddef>

#define S_LEN 250
#define BATCH 256
#define CIN   700
#define HID   256
#define OUT_N 20
#define KSTEPS 22   // ceil(700/32)

typedef __attribute__((ext_vector_type(8))) short bf16x8;
typedef __attribute__((ext_vector_type(4))) float f32x4;

__device__ __forceinline__ ushort f2bf_rne(float f) {
    uint u = __float_as_uint(f);
    uint r = (u + 0x7FFFu + ((u >> 16) & 1u)) >> 16;
    return (ushort)r;
}
__device__ __forceinline__ float bf2f(ushort h) {
    return __uint_as_float(((uint)h) << 16);
}

// ---------------------------------------------------------------------------
// Kernel 1: input projection GEMM via bf16x3 split MFMA (unchanged from R9,
// measured ~218us; bit-identical P output).
// ---------------------------------------------------------------------------
__global__ __launch_bounds__(256) void proj_mfma(
    const float* __restrict__ x,
    const float* __restrict__ Wf, const float* __restrict__ Wb,
    const float* __restrict__ biasf, const float* __restrict__ biasb,
    float* __restrict__ P)
{
    __shared__ ushort AsH[128][40];
    __shared__ ushort AsL[128][40];
    __shared__ ushort BsH[128][40];
    __shared__ ushort BsL[128][40];

    const int nt = blockIdx.x;
    const int mt = blockIdx.y;
    const int m0 = mt * 128;
    const float* W   = (nt < 2) ? Wf : Wb;
    const float* bia = (nt < 2) ? biasf : biasb;
    const int wc0 = (nt & 1) * 128;

    const int tid  = threadIdx.x;
    const int lane = tid & 63;
    const int wv   = tid >> 6;
    const int wr   = wv >> 1;
    const int wc   = wv & 1;
    const int l15  = lane & 15;
    const int l4   = lane >> 4;

    const int as  = tid & 7;
    const int arr = tid >> 3;
    const int bcol = tid & 127;
    const int bkh  = tid >> 7;

    f32x4 acc[4][4];
#pragma unroll
    for (int i = 0; i < 4; i++)
#pragma unroll
        for (int j = 0; j < 4; j++)
            acc[i][j] = (f32x4){0.f, 0.f, 0.f, 0.f};

    float4 av[4];
    float bv[16];

#define PROJ_LOAD(K0_) do {                                                   \
        const int ka_ = (K0_) + as * 4;                                       \
        const bool aok_ = (ka_ + 3) < CIN;                                    \
        _Pragma("unroll")                                                     \
        for (int i_ = 0; i_ < 4; i_++) {                                      \
            av[i_] = make_float4(0.f, 0.f, 0.f, 0.f);                         \
            if (aok_)                                                         \
                av[i_] = *(const float4*)&x[(size_t)(m0 + arr + 32 * i_) * CIN + ka_]; \
        }                                                                     \
        _Pragma("unroll")                                                     \
        for (int j_ = 0; j_ < 16; j_++) {                                     \
            const int kb_ = (K0_) + bkh * 16 + j_;                            \
            bv[j_] = (kb_ < CIN) ? W[(size_t)kb_ * HID + wc0 + bcol] : 0.f;   \
        }                                                                     \
    } while (0)

#define PROJ_CVT_WRITE() do {                                                 \
        _Pragma("unroll")                                                     \
        for (int i_ = 0; i_ < 4; i_++) {                                      \
            const int row_ = arr + 32 * i_;                                   \
            ushort4 h_, l_;                                                   \
            h_.x = f2bf_rne(av[i_].x); l_.x = f2bf_rne(__fsub_rn(av[i_].x, bf2f(h_.x))); \
            h_.y = f2bf_rne(av[i_].y); l_.y = f2bf_rne(__fsub_rn(av[i_].y, bf2f(h_.y))); \
            h_.z = f2bf_rne(av[i_].z); l_.z = f2bf_rne(__fsub_rn(av[i_].z, bf2f(h_.z))); \
            h_.w = f2bf_rne(av[i_].w); l_.w = f2bf_rne(__fsub_rn(av[i_].w, bf2f(h_.w))); \
            *(ushort4*)&AsH[row_][as * 4] = h_;                               \
            *(ushort4*)&AsL[row_][as * 4] = l_;                               \
        }                                                                     \
        _Pragma("unroll")                                                     \
        for (int q_ = 0; q_ < 4; q_++) {                                      \
            ushort4 h_, l_;                                                   \
            float v0_ = bv[q_ * 4 + 0], v1_ = bv[q_ * 4 + 1];                 \
            float v2_ = bv[q_ * 4 + 2], v3_ = bv[q_ * 4 + 3];                 \
            h_.x = f2bf_rne(v0_); l_.x = f2bf_rne(__fsub_rn(v0_, bf2f(h_.x))); \
            h_.y = f2bf_rne(v1_); l_.y = f2bf_rne(__fsub_rn(v1_, bf2f(h_.y))); \
            h_.z = f2bf_rne(v2_); l_.z = f2bf_rne(__fsub_rn(v2_, bf2f(h_.z))); \
            h_.w = f2bf_rne(v3_); l_.w = f2bf_rne(__fsub_rn(v3_, bf2f(h_.w))); \
            *(ushort4*)&BsH[bcol][bkh * 16 + q_ * 4] = h_;                    \
            *(ushort4*)&BsL[bcol][bkh * 16 + q_ * 4] = l_;                    \
        }                                                                     \
    } while (0)

    PROJ_LOAD(0);
    PROJ_CVT_WRITE();

    for (int kt = 0; kt < KSTEPS; kt++) {
        __syncthreads();
        if (kt + 1 < KSTEPS)
            PROJ_LOAD((kt + 1) * 32);

#pragma unroll
        for (int fc = 0; fc < 4; fc++) {
            const bf16x8 bHf = *(const bf16x8*)&BsH[wc * 64 + fc * 16 + l15][l4 * 8];
            const bf16x8 bLf = *(const bf16x8*)&BsL[wc * 64 + fc * 16 + l15][l4 * 8];
#pragma unroll
            for (int fr = 0; fr < 4; fr++) {
                const bf16x8 aHf = *(const bf16x8*)&AsH[wr * 64 + fr * 16 + l15][l4 * 8];
                const bf16x8 aLf = *(const bf16x8*)&AsL[wr * 64 + fr * 16 + l15][l4 * 8];
                acc[fr][fc] = __builtin_amdgcn_mfma_f32_16x16x32_bf16(
                    aHf, bHf, acc[fr][fc], 0, 0, 0);
                acc[fr][fc] = __builtin_amdgcn_mfma_f32_16x16x32_bf16(
                    aHf, bLf, acc[fr][fc], 0, 0, 0);
                acc[fr][fc] = __builtin_amdgcn_mfma_f32_16x16x32_bf16(
                    aLf, bHf, acc[fr][fc], 0, 0, 0);
            }
        }

        __syncthreads();
        if (kt + 1 < KSTEPS)
            PROJ_CVT_WRITE();
    }

#undef PROJ_LOAD
#undef PROJ_CVT_WRITE

#pragma unroll
    for (int fc = 0; fc < 4; fc++) {
        const float bvs = bia[wc0 + wc * 64 + fc * 16 + l15];
#pragma unroll
        for (int fr = 0; fr < 4; fr++) {
#pragma unroll
            for (int j = 0; j < 4; j++) {
                const int row = m0 + wr * 64 + fr * 16 + l4 * 4 + j;
                P[(size_t)row * 512 + nt * 128 + wc * 64 + fc * 16 + l15] =
                    __fadd_rn(acc[fr][fc][j], bvs);
            }
        }
    }
}

// ---------------------------------------------------------------------------
// Kernel 2: MFMA scan, register-neutral critical-path cuts vs R9 (303us):
//  - delayed readout (bit-exact, verified R7): S-MFMAs read Sp[prev] in the
//    main post-barrier phase; mid-step lgkmcnt(0)+sched_barrier deleted;
//    epilogue applies step S-1's readout.
//  - accH/accL split chains (+8 reg) paid for by dropping the pv double
//    buffer (-8 reg): stays at the 256-unified-reg cap for 512thr/2-waves-EU.
//  - incremental P row pointers (srow linear in s): ~30 VALU/step saved.
//  - unroll x2: Sp buffer indices compile-time.
// ---------------------------------------------------------------------------
__global__ __launch_bounds__(512, 2) void scan_mfma(
    const float* __restrict__ P,
    const float* __restrict__ Wrecf, const float* __restrict__ brecf,
    const float* __restrict__ taumf, const float* __restrict__ tauaf,
    const float* __restrict__ Wrecb, const float* __restrict__ brecb,
    const float* __restrict__ taumb, const float* __restrict__ tauab,
    const float* __restrict__ Wout, const float* __restrict__ taumo,
    float* __restrict__ Pst)
{
    const int g  = blockIdx.x;          // batch group: b0..b0+15
    const int d  = blockIdx.y;          // 0 = fw, 1 = bw
    const int b0 = g * 16;
    const bool fw = (d == 0);

    const int tid  = threadIdx.x;
    const int lane = tid & 63;
    const int w    = tid >> 6;          // wave 0..7
    const int l15  = lane & 15;
    const int l4   = lane >> 4;

    __shared__ ushort Sp[2][16][264];   // [buf][batch][col(+pad)] bf16 spikes

    {   // zero both spike buffers (step -1 spikes = 0)
        ushort* p = &Sp[0][0][0];
        for (int i = tid; i < 2 * 16 * 264; i += 512) p[i] = 0;
    }

    const float* Wrec = fw ? Wrecf : Wrecb;

    // ---- W_rec fragments (hi+lo bf16), register resident (128 AGPR)
    bf16x8 whf[8][2], wlf[8][2];
#pragma unroll
    for (int kt = 0; kt < 8; kt++)
#pragma unroll
        for (int ct = 0; ct < 2; ct++) {
            const int c = w * 32 + ct * 16 + l15;
#pragma unroll
            for (int j = 0; j < 8; j++) {
                const float v = Wrec[(size_t)(kt * 32 + l4 * 8 + j) * HID + c];
                const ushort h = f2bf_rne(v);
                const ushort l = f2bf_rne(__fsub_rn(v, bf2f(h)));
                whf[kt][ct][j] = (short)h;
                wlf[kt][ct][j] = (short)l;
            }
        }

    // ---- W_out fragments for this wave's 32-k slice (hi+lo)
    bf16x8 woh[2], wol[2];
#pragma unroll
    for (int t = 0; t < 2; t++) {
        const int o = t * 16 + l15;
#pragma unroll
        for (int j = 0; j < 8; j++) {
            float v = 0.f;
            if (o < OUT_N)
                v = Wout[(size_t)(d * HID + w * 32 + l4 * 8 + j) * OUT_N + o];
            const ushort h = f2bf_rne(v);
            const ushort l = f2bf_rne(__fsub_rn(v, bf2f(h)));
            woh[t][j] = (short)h;
            wol[t][j] = (short)l;
        }
    }

    // ---- LIF constants for this thread's 2 columns
    float alpha_[2], ro_[2], omA_[2], omR_[2], brc_[2];
#pragma unroll
    for (int t = 0; t < 2; t++) {
        const int c = w * 32 + t * 16 + l15;
        alpha_[t] = expf(__fdiv_rn(-1.f, fw ? taumf[c] : taumb[c]));
        ro_[t]    = expf(__fdiv_rn(-1.f, fw ? tauaf[c] : tauab[c]));
        omA_[t]   = __fsub_rn(1.f, alpha_[t]);
        omR_[t]   = __fsub_rn(1.f, ro_[t]);
        brc_[t]   = fw ? brecf[c] : brecb[c];
    }
    // ---- readout constants
    float ao_[2], omo_[2];
#pragma unroll
    for (int t = 0; t < 2; t++) {
        const int o = t * 16 + l15;
        if (o < OUT_N) {
            ao_[t]  = expf(__fdiv_rn(-1.f, taumo[o]));
            omo_[t] = __fsub_rn(1.f, ao_[t]);
        } else { ao_[t] = 0.f; omo_[t] = 0.f; }
    }

    float mem[2][4], bbv[2][4], spkv[2][4], z[2][4];
#pragma unroll
    for (int t = 0; t < 2; t++)
#pragma unroll
        for (int j = 0; j < 4; j++) {
            mem[t][j] = 0.f; bbv[t][j] = 0.01f; spkv[t][j] = 0.f; z[t][j] = 0.f;
        }

    // ---- incremental P row pointers (one per j-row); advance +-512 floats
    const float* pp0 = P + ((size_t)(b0 + l4 * 4 + 0) * S_LEN + (fw ? 0 : S_LEN - 1)) * 512
                         + d * HID + w * 32 + l15;
    const float* pp1 = P + ((size_t)(b0 + l4 * 4 + 1) * S_LEN + (fw ? 0 : S_LEN - 1)) * 512
                         + d * HID + w * 32 + l15;
    const float* pp2 = P + ((size_t)(b0 + l4 * 4 + 2) * S_LEN + (fw ? 0 : S_LEN - 1)) * 512
                         + d * HID + w * 32 + l15;
    const float* pp3 = P + ((size_t)(b0 + l4 * 4 + 3) * S_LEN + (fw ? 0 : S_LEN - 1)) * 512
                         + d * HID + w * 32 + l15;
    const ptrdiff_t pstep = fw ? 512 : -512;

    float pv[2][4];

#define SCAN_STEP(CUR, PREV) do {                                              \
        __syncthreads();   /* Sp[PREV] complete; prior reads of Sp[CUR] done */\
        /* pv loads for THIS step: latency hides under the MFMA phase */       \
        pv[0][0] = pp0[0];  pv[1][0] = pp0[16];                                \
        pv[0][1] = pp1[0];  pv[1][1] = pp1[16];                                \
        pv[0][2] = pp2[0];  pv[1][2] = pp2[16];                                \
        pv[0][3] = pp3[0];  pv[1][3] = pp3[16];                                \
        pp0 += pstep; pp1 += pstep; pp2 += pstep; pp3 += pstep;                \
        f32x4 accH0 = (f32x4){0.f,0.f,0.f,0.f}, accH1 = (f32x4){0.f,0.f,0.f,0.f}; \
        f32x4 accL0 = (f32x4){0.f,0.f,0.f,0.f}, accL1 = (f32x4){0.f,0.f,0.f,0.f}; \
        _Pragma("unroll")                                                      \
        for (int kt_ = 0; kt_ < 8; kt_++) {                                    \
            const bf16x8 a_ = *(const bf16x8*)&Sp[PREV][l15][kt_ * 32 + l4 * 8]; \
            accH0 = __builtin_amdgcn_mfma_f32_16x16x32_bf16(a_, whf[kt_][0], accH0, 0, 0, 0); \
            accL0 = __builtin_amdgcn_mfma_f32_16x16x32_bf16(a_, wlf[kt_][0], accL0, 0, 0, 0); \
            accH1 = __builtin_amdgcn_mfma_f32_16x16x32_bf16(a_, whf[kt_][1], accH1, 0, 0, 0); \
            accL1 = __builtin_amdgcn_mfma_f32_16x16x32_bf16(a_, wlf[kt_][1], accL1, 0, 0, 0); \
        }                                                                      \
        /* delayed readout of step's PREV spikes: wave-local a-frag */         \
        {                                                                      \
            const bf16x8 ar_ = *(const bf16x8*)&Sp[PREV][l15][w * 32 + l4 * 8]; \
            f32x4 S0_ = (f32x4){0.f,0.f,0.f,0.f}, S1_ = (f32x4){0.f,0.f,0.f,0.f}; \
            S0_ = __builtin_amdgcn_mfma_f32_16x16x32_bf16(ar_, woh[0], S0_, 0, 0, 0); \
            S0_ = __builtin_amdgcn_mfma_f32_16x16x32_bf16(ar_, wol[0], S0_, 0, 0, 0); \
            S1_ = __builtin_amdgcn_mfma_f32_16x16x32_bf16(ar_, woh[1], S1_, 0, 0, 0); \
            S1_ = __builtin_amdgcn_mfma_f32_16x16x32_bf16(ar_, wol[1], S1_, 0, 0, 0); \
            _Pragma("unroll")                                                  \
            for (int j_ = 0; j_ < 4; j_++) {                                   \
                z[0][j_] = __fmaf_rn(ao_[0], z[0][j_], __fmul_rn(omo_[0], S0_[j_])); \
                z[1][j_] = __fmaf_rn(ao_[1], z[1][j_], __fmul_rn(omo_[1], S1_[j_])); \
            }                                                                  \
        }                                                                      \
        /* adaptive-LIF update (exact reference rounding order) */             \
        _Pragma("unroll")                                                      \
        for (int t_ = 0; t_ < 2; t_++) {                                       \
            _Pragma("unroll")                                                  \
            for (int j_ = 0; j_ < 4; j_++) {                                   \
                const float accv_ = __fadd_rn((t_ ? accH1 : accH0)[j_],        \
                                              (t_ ? accL1 : accL0)[j_]);       \
                const float dd_ = __fadd_rn(__fadd_rn(pv[t_][j_], accv_), brc_[t_]); \
                bbv[t_][j_] = __fadd_rn(__fmul_rn(ro_[t_], bbv[t_][j_]),       \
                                        __fmul_rn(omR_[t_], spkv[t_][j_]));    \
                const float thr_ = __fadd_rn(0.01f, __fmul_rn(1.8f, bbv[t_][j_])); \
                mem[t_][j_] = __fsub_rn(                                       \
                    __fadd_rn(__fmul_rn(mem[t_][j_], alpha_[t_]),              \
                              __fmul_rn(omA_[t_], dd_)),                       \
                    __fmul_rn(thr_, spkv[t_][j_]));                            \
                const bool sp_ = __fsub_rn(mem[t_][j_], thr_) > 0.f;           \
                spkv[t_][j_] = sp_ ? 1.f : 0.f;                                \
                Sp[CUR][l4 * 4 + j_][w * 32 + t_ * 16 + l15] =                 \
                    sp_ ? (ushort)0x3F80 : (ushort)0;                          \
            }                                                                  \
        }                                                                      \
    } while (0)

    for (int s2 = 0; s2 < S_LEN / 2; s2++) {
        SCAN_STEP(0, 1);   // even step: cur=0, prev=1
        SCAN_STEP(1, 0);   // odd  step: cur=1, prev=0
    }
#undef SCAN_STEP

    // own-wave visibility of the last ds_writes (readout frag is wave-local)
    asm volatile("s_waitcnt lgkmcnt(0)" ::: "memory");
    __builtin_amdgcn_sched_barrier(0);

    // ---- epilogue: readout update with y_{S-1} (spk(249) in buffer 1)
    {
        const bf16x8 ar = *(const bf16x8*)&Sp[1][l15][w * 32 + l4 * 8];
        f32x4 S0 = (f32x4){0.f, 0.f, 0.f, 0.f};
        f32x4 S1 = (f32x4){0.f, 0.f, 0.f, 0.f};
        S0 = __builtin_amdgcn_mfma_f32_16x16x32_bf16(ar, woh[0], S0, 0, 0, 0);
        S0 = __builtin_amdgcn_mfma_f32_16x16x32_bf16(ar, wol[0], S0, 0, 0, 0);
        S1 = __builtin_amdgcn_mfma_f32_16x16x32_bf16(ar, woh[1], S1, 0, 0, 0);
        S1 = __builtin_amdgcn_mfma_f32_16x16x32_bf16(ar, wol[1], S1, 0, 0, 0);
#pragma unroll
        for (int j = 0; j < 4; j++) {
            z[0][j] = __fmaf_rn(ao_[0], z[0][j], __fmul_rn(omo_[0], S0[j]));
            z[1][j] = __fmaf_rn(ao_[1], z[1][j], __fmul_rn(omo_[1], S1[j]));
        }
    }

    __syncthreads();   // all waves done reading P rows we now overwrite

    // ---- stash per-wave readout partials into consumed P rows
    float* stash = Pst + ((size_t)b0 * S_LEN) * 512 + d * HID;
#pragma unroll
    for (int j = 0; j < 4; j++) {
        const int r = l4 * 4 + j;
        const int idx0 = w * 320 + r * 16 + l15;
        stash[(size_t)(idx0 >> 8) * 512 + (idx0 & 255)] = z[0][j];
        if (l15 < 4) {
            const int idx1 = w * 320 + 256 + r * 4 + l15;
            stash[(size_t)(idx1 >> 8) * 512 + (idx1 & 255)] = z[1][j];
        }
    }
}

// ---------------------------------------------------------------------------
// Kernel 3: merge stashed partials + bias closed form + log_softmax.
// ---------------------------------------------------------------------------
__global__ __launch_bounds__(64) void merge_out(
    const float* __restrict__ Pst, const float* __restrict__ bout,
    const float* __restrict__ taumo, float* __restrict__ out)
{
    const int bb = blockIdx.x;
    const int o  = threadIdx.x;         // active 0..19
    const int g  = bb >> 4, r = bb & 15;

    float val = 0.f, v = -3.0e38f;
    if (o < OUT_N) {
        float tot = 0.f;
#pragma unroll
        for (int d2 = 0; d2 < 2; d2++) {
            const float* stash = Pst + ((size_t)(g * 16) * S_LEN) * 512 + d2 * HID;
#pragma unroll
            for (int w2 = 0; w2 < 8; w2++) {
                const int idx = (o < 16) ? (w2 * 320 + r * 16 + o)
                                         : (w2 * 320 + 256 + r * 4 + (o - 16));
                tot = __fadd_rn(tot, stash[(size_t)(idx >> 8) * 512 + (idx & 255)]);
            }
        }
        const float aS = expf(__fdiv_rn(-(float)S_LEN, taumo[o]));
        val = __fadd_rn(tot, __fmul_rn(bout[o], __fsub_rn(1.f, aS)));
        v = val;
    }
    float mx = v;
#pragma unroll
    for (int d2 = 1; d2 < 64; d2 <<= 1)
        mx = fmaxf(mx, __shfl_xor(mx, d2, 64));
    float e = (o < OUT_N) ? expf(__fsub_rn(val, mx)) : 0.f;
#pragma unroll
    for (int d2 = 1; d2 < 64; d2 <<= 1)
        e += __shfl_xor(e, d2, 64);
    if (o < OUT_N)
        out[(size_t)bb * OUT_N + o] =
            __fsub_rn(__fsub_rn(val, mx), logf(e));
}

// ---------------------------------------------------------------------------
extern "C" void kernel_launch(void* const* d_in, const int* in_sizes, int n_in,
                              void* d_out, int out_size, void* d_ws, size_t ws_size,
                              hipStream_t stream) {
    const float* x         = (const float*)d_in[0];
    const float* W_in_f    = (const float*)d_in[1];
    const float* b_in_f    = (const float*)d_in[2];
    const float* W_rec_f   = (const float*)d_in[3];
    const float* b_rec_f   = (const float*)d_in[4];
    const float* tau_m_f   = (const float*)d_in[5];
    const float* tau_adp_f = (const float*)d_in[6];
    const float* W_in_b    = (const float*)d_in[7];
    const float* b_in_b    = (const float*)d_in[8];
    const float* W_rec_b   = (const float*)d_in[9];
    const float* b_rec_b   = (const float*)d_in[10];
    const float* tau_m_b   = (const float*)d_in[11];
    const float* tau_adp_b = (const float*)d_in[12];
    const float* W_out     = (const float*)d_in[13];
    const float* b_out     = (const float*)d_in[14];
    const float* tau_m_o   = (const float*)d_in[15];
    float* out = (float*)d_out;
    float* P   = (float*)d_ws;

    proj_mfma<<<dim3(4, 500), dim3(256), 0, stream>>>(
        x, W_in_f, W_in_b, b_in_f, b_in_b, P);
    scan_mfma<<<dim3(16, 2), dim3(512), 0, stream>>>(
        P, W_rec_f, b_rec_f, tau_m_f, tau_adp_f,
        W_rec_b, b_rec_b, tau_m_b, tau_adp_b,
        W_out, tau_m_o, P);
    merge_out<<<dim3(BATCH), dim3(64), 0, stream>>>(
        P, b_out, tau_m_o, out);
}

// Round 13
// 524.616 us; speedup vs baseline: 1.1860x; 1.1860x over previous
//
#include <hip/hip_runtime.h>
#include <cstdint>
#include <cstddef>

#define S_LEN 250
#define BATCH 256
#define CIN   700
#define HID   256
#define OUT_N 20
#define KSTEPS 22   // ceil(700/32)

typedef __attribute__((ext_vector_type(8))) short bf16x8;
typedef __attribute__((ext_vector_type(4))) float f32x4;

__device__ __forceinline__ ushort f2bf_rne(float f) {
    uint u = __float_as_uint(f);
    uint r = (u + 0x7FFFu + ((u >> 16) & 1u)) >> 16;
    return (ushort)r;
}
__device__ __forceinline__ float bf2f(ushort h) {
    return __uint_as_float(((uint)h) << 16);
}

// ---------------------------------------------------------------------------
// Kernel 1: input projection GEMM via bf16x3 split MFMA (unchanged from R9,
// measured ~218us; bit-identical P output).
// ---------------------------------------------------------------------------
__global__ __launch_bounds__(256) void proj_mfma(
    const float* __restrict__ x,
    const float* __restrict__ Wf, const float* __restrict__ Wb,
    const float* __restrict__ biasf, const float* __restrict__ biasb,
    float* __restrict__ P)
{
    __shared__ ushort AsH[128][40];
    __shared__ ushort AsL[128][40];
    __shared__ ushort BsH[128][40];
    __shared__ ushort BsL[128][40];

    const int nt = blockIdx.x;
    const int mt = blockIdx.y;
    const int m0 = mt * 128;
    const float* W   = (nt < 2) ? Wf : Wb;
    const float* bia = (nt < 2) ? biasf : biasb;
    const int wc0 = (nt & 1) * 128;

    const int tid  = threadIdx.x;
    const int lane = tid & 63;
    const int wv   = tid >> 6;
    const int wr   = wv >> 1;
    const int wc   = wv & 1;
    const int l15  = lane & 15;
    const int l4   = lane >> 4;

    const int as  = tid & 7;
    const int arr = tid >> 3;
    const int bcol = tid & 127;
    const int bkh  = tid >> 7;

    f32x4 acc[4][4];
#pragma unroll
    for (int i = 0; i < 4; i++)
#pragma unroll
        for (int j = 0; j < 4; j++)
            acc[i][j] = (f32x4){0.f, 0.f, 0.f, 0.f};

    float4 av[4];
    float bv[16];

#define PROJ_LOAD(K0_) do {                                                   \
        const int ka_ = (K0_) + as * 4;                                       \
        const bool aok_ = (ka_ + 3) < CIN;                                    \
        _Pragma("unroll")                                                     \
        for (int i_ = 0; i_ < 4; i_++) {                                      \
            av[i_] = make_float4(0.f, 0.f, 0.f, 0.f);                         \
            if (aok_)                                                         \
                av[i_] = *(const float4*)&x[(size_t)(m0 + arr + 32 * i_) * CIN + ka_]; \
        }                                                                     \
        _Pragma("unroll")                                                     \
        for (int j_ = 0; j_ < 16; j_++) {                                     \
            const int kb_ = (K0_) + bkh * 16 + j_;                            \
            bv[j_] = (kb_ < CIN) ? W[(size_t)kb_ * HID + wc0 + bcol] : 0.f;   \
        }                                                                     \
    } while (0)

#define PROJ_CVT_WRITE() do {                                                 \
        _Pragma("unroll")                                                     \
        for (int i_ = 0; i_ < 4; i_++) {                                      \
            const int row_ = arr + 32 * i_;                                   \
            ushort4 h_, l_;                                                   \
            h_.x = f2bf_rne(av[i_].x); l_.x = f2bf_rne(__fsub_rn(av[i_].x, bf2f(h_.x))); \
            h_.y = f2bf_rne(av[i_].y); l_.y = f2bf_rne(__fsub_rn(av[i_].y, bf2f(h_.y))); \
            h_.z = f2bf_rne(av[i_].z); l_.z = f2bf_rne(__fsub_rn(av[i_].z, bf2f(h_.z))); \
            h_.w = f2bf_rne(av[i_].w); l_.w = f2bf_rne(__fsub_rn(av[i_].w, bf2f(h_.w))); \
            *(ushort4*)&AsH[row_][as * 4] = h_;                               \
            *(ushort4*)&AsL[row_][as * 4] = l_;                               \
        }                                                                     \
        _Pragma("unroll")                                                     \
        for (int q_ = 0; q_ < 4; q_++) {                                      \
            ushort4 h_, l_;                                                   \
            float v0_ = bv[q_ * 4 + 0], v1_ = bv[q_ * 4 + 1];                 \
            float v2_ = bv[q_ * 4 + 2], v3_ = bv[q_ * 4 + 3];                 \
            h_.x = f2bf_rne(v0_); l_.x = f2bf_rne(__fsub_rn(v0_, bf2f(h_.x))); \
            h_.y = f2bf_rne(v1_); l_.y = f2bf_rne(__fsub_rn(v1_, bf2f(h_.y))); \
            h_.z = f2bf_rne(v2_); l_.z = f2bf_rne(__fsub_rn(v2_, bf2f(h_.z))); \
            h_.w = f2bf_rne(v3_); l_.w = f2bf_rne(__fsub_rn(v3_, bf2f(h_.w))); \
            *(ushort4*)&BsH[bcol][bkh * 16 + q_ * 4] = h_;                    \
            *(ushort4*)&BsL[bcol][bkh * 16 + q_ * 4] = l_;                    \
        }                                                                     \
    } while (0)

    PROJ_LOAD(0);
    PROJ_CVT_WRITE();

    for (int kt = 0; kt < KSTEPS; kt++) {
        __syncthreads();
        if (kt + 1 < KSTEPS)
            PROJ_LOAD((kt + 1) * 32);

#pragma unroll
        for (int fc = 0; fc < 4; fc++) {
            const bf16x8 bHf = *(const bf16x8*)&BsH[wc * 64 + fc * 16 + l15][l4 * 8];
            const bf16x8 bLf = *(const bf16x8*)&BsL[wc * 64 + fc * 16 + l15][l4 * 8];
#pragma unroll
            for (int fr = 0; fr < 4; fr++) {
                const bf16x8 aHf = *(const bf16x8*)&AsH[wr * 64 + fr * 16 + l15][l4 * 8];
                const bf16x8 aLf = *(const bf16x8*)&AsL[wr * 64 + fr * 16 + l15][l4 * 8];
                acc[fr][fc] = __builtin_amdgcn_mfma_f32_16x16x32_bf16(
                    aHf, bHf, acc[fr][fc], 0, 0, 0);
                acc[fr][fc] = __builtin_amdgcn_mfma_f32_16x16x32_bf16(
                    aHf, bLf, acc[fr][fc], 0, 0, 0);
                acc[fr][fc] = __builtin_amdgcn_mfma_f32_16x16x32_bf16(
                    aLf, bHf, acc[fr][fc], 0, 0, 0);
            }
        }

        __syncthreads();
        if (kt + 1 < KSTEPS)
            PROJ_CVT_WRITE();
    }

#undef PROJ_LOAD
#undef PROJ_CVT_WRITE

#pragma unroll
    for (int fc = 0; fc < 4; fc++) {
        const float bvs = bia[wc0 + wc * 64 + fc * 16 + l15];
#pragma unroll
        for (int fr = 0; fr < 4; fr++) {
#pragma unroll
            for (int j = 0; j < 4; j++) {
                const int row = m0 + wr * 64 + fr * 16 + l4 * 4 + j;
                P[(size_t)row * 512 + nt * 128 + wc * 64 + fc * 16 + l15] =
                    __fadd_rn(acc[fr][fc][j], bvs);
            }
        }
    }
}

// ---------------------------------------------------------------------------
// Kernel 2: MFMA scan — EXACT R6 structure (best measured: 294us, absmax
// 0.0625) with ONE isolated change: DELAYED READOUT. The 4 readout MFMAs now
// read Sp[prev] in the same post-barrier phase as the recurrent MFMAs,
// deleting the mid-step lgkmcnt(0) drain + second LDS round-trip + trailing
// dependent MFMA chain. z-update sequence is bit-exact (the extra first
// update multiplies exact zeros; epilogue applies step S-1's readout) —
// numerically confirmed in R7/R10 (absmax unchanged).
// Everything else identical to R6: pv_next prefetch issued BEFORE the
// barrier (one full step of latency hiding), single 16-deep acc chains
// (no register growth), pitch-264 Sp, 128 VGPR + 128 AGPR = 256-reg cap.
// ---------------------------------------------------------------------------
__global__ __launch_bounds__(512, 2) void scan_mfma(
    const float* __restrict__ P,
    const float* __restrict__ Wrecf, const float* __restrict__ brecf,
    const float* __restrict__ taumf, const float* __restrict__ tauaf,
    const float* __restrict__ Wrecb, const float* __restrict__ brecb,
    const float* __restrict__ taumb, const float* __restrict__ tauab,
    const float* __restrict__ Wout, const float* __restrict__ taumo,
    float* __restrict__ Pst)
{
    const int g  = blockIdx.x;          // batch group: b0..b0+15
    const int d  = blockIdx.y;          // 0 = fw, 1 = bw
    const int b0 = g * 16;
    const bool fw = (d == 0);

    const int tid  = threadIdx.x;
    const int lane = tid & 63;
    const int w    = tid >> 6;          // wave 0..7
    const int l15  = lane & 15;
    const int l4   = lane >> 4;

    __shared__ ushort Sp[2][16][264];   // [buf][batch][col(+pad)] bf16 spikes

    {   // zero both spike buffers (step -1 spikes = 0)
        ushort* p = &Sp[0][0][0];
        for (int i = tid; i < 2 * 16 * 264; i += 512) p[i] = 0;
    }

    const float* Wrec = fw ? Wrecf : Wrecb;

    // ---- W_rec fragments (hi+lo bf16), register resident
    bf16x8 whf[8][2], wlf[8][2];
#pragma unroll
    for (int kt = 0; kt < 8; kt++)
#pragma unroll
        for (int ct = 0; ct < 2; ct++) {
            const int c = w * 32 + ct * 16 + l15;
#pragma unroll
            for (int j = 0; j < 8; j++) {
                const float v = Wrec[(size_t)(kt * 32 + l4 * 8 + j) * HID + c];
                const ushort h = f2bf_rne(v);
                const ushort l = f2bf_rne(__fsub_rn(v, bf2f(h)));
                whf[kt][ct][j] = (short)h;
                wlf[kt][ct][j] = (short)l;
            }
        }

    // ---- W_out fragments for this wave's 32-k slice (hi+lo)
    bf16x8 woh[2], wol[2];
#pragma unroll
    for (int t = 0; t < 2; t++) {
        const int o = t * 16 + l15;
#pragma unroll
        for (int j = 0; j < 8; j++) {
            float v = 0.f;
            if (o < OUT_N)
                v = Wout[(size_t)(d * HID + w * 32 + l4 * 8 + j) * OUT_N + o];
            const ushort h = f2bf_rne(v);
            const ushort l = f2bf_rne(__fsub_rn(v, bf2f(h)));
            woh[t][j] = (short)h;
            wol[t][j] = (short)l;
        }
    }

    // ---- LIF constants for this thread's 2 columns
    float alpha_[2], ro_[2], omA_[2], omR_[2], brc_[2];
#pragma unroll
    for (int t = 0; t < 2; t++) {
        const int c = w * 32 + t * 16 + l15;
        alpha_[t] = expf(__fdiv_rn(-1.f, fw ? taumf[c] : taumb[c]));
        ro_[t]    = expf(__fdiv_rn(-1.f, fw ? tauaf[c] : tauab[c]));
        omA_[t]   = __fsub_rn(1.f, alpha_[t]);
        omR_[t]   = __fsub_rn(1.f, ro_[t]);
        brc_[t]   = fw ? brecf[c] : brecb[c];
    }
    // ---- readout constants
    float ao_[2], omo_[2];
#pragma unroll
    for (int t = 0; t < 2; t++) {
        const int o = t * 16 + l15;
        if (o < OUT_N) {
            ao_[t]  = expf(__fdiv_rn(-1.f, taumo[o]));
            omo_[t] = __fsub_rn(1.f, ao_[t]);
        } else { ao_[t] = 0.f; omo_[t] = 0.f; }
    }

    float mem[2][4], bbv[2][4], spkv[2][4], z[2][4];
#pragma unroll
    for (int t = 0; t < 2; t++)
#pragma unroll
        for (int j = 0; j < 4; j++) {
            mem[t][j] = 0.f; bbv[t][j] = 0.01f; spkv[t][j] = 0.f; z[t][j] = 0.f;
        }

    // pv prefetch for s=0
    float pv[2][4];
    {
        const int srow = fw ? 0 : (S_LEN - 1);
#pragma unroll
        for (int t = 0; t < 2; t++)
#pragma unroll
            for (int j = 0; j < 4; j++)
                pv[t][j] = P[((size_t)(b0 + l4 * 4 + j) * S_LEN + srow) * 512
                             + d * HID + w * 32 + t * 16 + l15];
    }

    for (int s = 0; s < S_LEN; s++) {
        const int cur = s & 1, prev = cur ^ 1;

        // prefetch next step's projection BEFORE the barrier (R6 exact form:
        // one full step for the latency to drain)
        float pv_next[2][4];
        {
            const int sn   = (s + 1 < S_LEN) ? s + 1 : S_LEN - 1;
            const int srow = fw ? sn : (S_LEN - 1 - sn);
#pragma unroll
            for (int t = 0; t < 2; t++)
#pragma unroll
                for (int j = 0; j < 4; j++)
                    pv_next[t][j] = P[((size_t)(b0 + l4 * 4 + j) * S_LEN + srow) * 512
                                      + d * HID + w * 32 + t * 16 + l15];
        }

        __syncthreads();   // Sp[prev] complete from all waves

        // ---- recurrent GEMM: D[batch][col] += spk(prev) @ W_rec
        f32x4 acc[2];
        acc[0] = (f32x4){0.f, 0.f, 0.f, 0.f};
        acc[1] = (f32x4){0.f, 0.f, 0.f, 0.f};
#pragma unroll
        for (int kt = 0; kt < 8; kt++) {
            const bf16x8 a = *(const bf16x8*)&Sp[prev][l15][kt * 32 + l4 * 8];
            acc[0] = __builtin_amdgcn_mfma_f32_16x16x32_bf16(a, whf[kt][0], acc[0], 0, 0, 0);
            acc[0] = __builtin_amdgcn_mfma_f32_16x16x32_bf16(a, wlf[kt][0], acc[0], 0, 0, 0);
            acc[1] = __builtin_amdgcn_mfma_f32_16x16x32_bf16(a, whf[kt][1], acc[1], 0, 0, 0);
            acc[1] = __builtin_amdgcn_mfma_f32_16x16x32_bf16(a, wlf[kt][1], acc[1], 0, 0, 0);
        }

        // ---- DELAYED readout: y_{s-1} from Sp[prev] (same phase, no extra
        // sync needed; Sp[prev] already visible via the barrier)
        {
            const bf16x8 ar = *(const bf16x8*)&Sp[prev][l15][w * 32 + l4 * 8];
            f32x4 S0 = (f32x4){0.f, 0.f, 0.f, 0.f};
            f32x4 S1 = (f32x4){0.f, 0.f, 0.f, 0.f};
            S0 = __builtin_amdgcn_mfma_f32_16x16x32_bf16(ar, woh[0], S0, 0, 0, 0);
            S0 = __builtin_amdgcn_mfma_f32_16x16x32_bf16(ar, wol[0], S0, 0, 0, 0);
            S1 = __builtin_amdgcn_mfma_f32_16x16x32_bf16(ar, woh[1], S1, 0, 0, 0);
            S1 = __builtin_amdgcn_mfma_f32_16x16x32_bf16(ar, wol[1], S1, 0, 0, 0);
#pragma unroll
            for (int j = 0; j < 4; j++) {
                z[0][j] = __fmaf_rn(ao_[0], z[0][j], __fmul_rn(omo_[0], S0[j]));
                z[1][j] = __fmaf_rn(ao_[1], z[1][j], __fmul_rn(omo_[1], S1[j]));
            }
        }

        // ---- adaptive-LIF update on the C/D fragment (exact ref rounding)
#pragma unroll
        for (int t = 0; t < 2; t++) {
#pragma unroll
            for (int j = 0; j < 4; j++) {
                const float dd = __fadd_rn(__fadd_rn(pv[t][j], acc[t][j]), brc_[t]);
                bbv[t][j] = __fadd_rn(__fmul_rn(ro_[t], bbv[t][j]),
                                      __fmul_rn(omR_[t], spkv[t][j]));
                const float thr = __fadd_rn(0.01f, __fmul_rn(1.8f, bbv[t][j]));
                mem[t][j] = __fsub_rn(
                    __fadd_rn(__fmul_rn(mem[t][j], alpha_[t]),
                              __fmul_rn(omA_[t], dd)),
                    __fmul_rn(thr, spkv[t][j]));
                const bool sp = __fsub_rn(mem[t][j], thr) > 0.f;
                spkv[t][j] = sp ? 1.f : 0.f;
                Sp[cur][l4 * 4 + j][w * 32 + t * 16 + l15] =
                    sp ? (ushort)0x3F80 : (ushort)0;
            }
        }

#pragma unroll
        for (int t = 0; t < 2; t++)
#pragma unroll
            for (int j = 0; j < 4; j++) pv[t][j] = pv_next[t][j];
    }

    // own-wave visibility of last ds_writes (readout frag is wave-local:
    // cols w*32..+31 are written exclusively by wave w)
    asm volatile("s_waitcnt lgkmcnt(0)" ::: "memory");
    __builtin_amdgcn_sched_barrier(0);

    // ---- epilogue: final readout update with y_{S-1} (spk(249) in buf 1)
    {
        const bf16x8 ar = *(const bf16x8*)&Sp[1][l15][w * 32 + l4 * 8];
        f32x4 S0 = (f32x4){0.f, 0.f, 0.f, 0.f};
        f32x4 S1 = (f32x4){0.f, 0.f, 0.f, 0.f};
        S0 = __builtin_amdgcn_mfma_f32_16x16x32_bf16(ar, woh[0], S0, 0, 0, 0);
        S0 = __builtin_amdgcn_mfma_f32_16x16x32_bf16(ar, wol[0], S0, 0, 0, 0);
        S1 = __builtin_amdgcn_mfma_f32_16x16x32_bf16(ar, woh[1], S1, 0, 0, 0);
        S1 = __builtin_amdgcn_mfma_f32_16x16x32_bf16(ar, wol[1], S1, 0, 0, 0);
#pragma unroll
        for (int j = 0; j < 4; j++) {
            z[0][j] = __fmaf_rn(ao_[0], z[0][j], __fmul_rn(omo_[0], S0[j]));
            z[1][j] = __fmaf_rn(ao_[1], z[1][j], __fmul_rn(omo_[1], S1[j]));
        }
    }

    __syncthreads();   // all waves done reading P rows we now overwrite

    // ---- stash per-wave readout partials into consumed P rows
    float* stash = Pst + ((size_t)b0 * S_LEN) * 512 + d * HID;
#pragma unroll
    for (int j = 0; j < 4; j++) {
        const int r = l4 * 4 + j;
        const int idx0 = w * 320 + r * 16 + l15;
        stash[(size_t)(idx0 >> 8) * 512 + (idx0 & 255)] = z[0][j];
        if (l15 < 4) {
            const int idx1 = w * 320 + 256 + r * 4 + l15;
            stash[(size_t)(idx1 >> 8) * 512 + (idx1 & 255)] = z[1][j];
        }
    }
}

// ---------------------------------------------------------------------------
// Kernel 3: merge stashed partials + bias closed form + log_softmax.
// ---------------------------------------------------------------------------
__global__ __launch_bounds__(64) void merge_out(
    const float* __restrict__ Pst, const float* __restrict__ bout,
    const float* __restrict__ taumo, float* __restrict__ out)
{
    const int bb = blockIdx.x;
    const int o  = threadIdx.x;         // active 0..19
    const int g  = bb >> 4, r = bb & 15;

    float val = 0.f, v = -3.0e38f;
    if (o < OUT_N) {
        float tot = 0.f;
#pragma unroll
        for (int d2 = 0; d2 < 2; d2++) {
            const float* stash = Pst + ((size_t)(g * 16) * S_LEN) * 512 + d2 * HID;
#pragma unroll
            for (int w2 = 0; w2 < 8; w2++) {
                const int idx = (o < 16) ? (w2 * 320 + r * 16 + o)
                                         : (w2 * 320 + 256 + r * 4 + (o - 16));
                tot = __fadd_rn(tot, stash[(size_t)(idx >> 8) * 512 + (idx & 255)]);
            }
        }
        const float aS = expf(__fdiv_rn(-(float)S_LEN, taumo[o]));
        val = __fadd_rn(tot, __fmul_rn(bout[o], __fsub_rn(1.f, aS)));
        v = val;
    }
    float mx = v;
#pragma unroll
    for (int d2 = 1; d2 < 64; d2 <<= 1)
        mx = fmaxf(mx, __shfl_xor(mx, d2, 64));
    float e = (o < OUT_N) ? expf(__fsub_rn(val, mx)) : 0.f;
#pragma unroll
    for (int d2 = 1; d2 < 64; d2 <<= 1)
        e += __shfl_xor(e, d2, 64);
    if (o < OUT_N)
        out[(size_t)bb * OUT_N + o] =
            __fsub_rn(__fsub_rn(val, mx), logf(e));
}

// ---------------------------------------------------------------------------
extern "C" void kernel_launch(void* const* d_in, const int* in_sizes, int n_in,
                              void* d_out, int out_size, void* d_ws, size_t ws_size,
                              hipStream_t stream) {
    const float* x         = (const float*)d_in[0];
    const float* W_in_f    = (const float*)d_in[1];
    const float* b_in_f    = (const float*)d_in[2];
    const float* W_rec_f   = (const float*)d_in[3];
    const float* b_rec_f   = (const float*)d_in[4];
    const float* tau_m_f   = (const float*)d_in[5];
    const float* tau_adp_f = (const float*)d_in[6];
    const float* W_in_b    = (const float*)d_in[7];
    const float* b_in_b    = (const float*)d_in[8];
    const float* W_rec_b   = (const float*)d_in[9];
    const float* b_rec_b   = (const float*)d_in[10];
    const float* tau_m_b   = (const float*)d_in[11];
    const float* tau_adp_b = (const float*)d_in[12];
    const float* W_out     = (const float*)d_in[13];
    const float* b_out     = (const float*)d_in[14];
    const float* tau_m_o   = (const float*)d_in[15];
    float* out = (float*)d_out;
    float* P   = (float*)d_ws;

    proj_mfma<<<dim3(4, 500), dim3(256), 0, stream>>>(
        x, W_in_f, W_in_b, b_in_f, b_in_b, P);
    scan_mfma<<<dim3(16, 2), dim3(512), 0, stream>>>(
        P, W_rec_f, b_rec_f, tau_m_f, tau_adp_f,
        W_rec_b, b_rec_b, tau_m_b, tau_adp_b,
        W_out, tau_m_o, P);
    merge_out<<<dim3(BATCH), dim3(64), 0, stream>>>(
        P, b_out, tau_m_o, out);
}

// Round 14
// 455.107 us; speedup vs baseline: 1.3672x; 1.1527x over previous
//
#include <hip/hip_runtime.h>
#include <cstdint>
#include <cstddef>

#define S_LEN 250
#define BATCH 256
#define CIN   700
#define HID   256
#define OUT_N 20
#define KSTEPS 22   // ceil(700/32)

typedef __attribute__((ext_vector_type(8))) short bf16x8;
typedef __attribute__((ext_vector_type(4))) float f32x4;

__device__ __forceinline__ ushort f2bf_rne(float f) {
    uint u = __float_as_uint(f);
    uint r = (u + 0x7FFFu + ((u >> 16) & 1u)) >> 16;
    return (ushort)r;
}
__device__ __forceinline__ float bf2f(ushort h) {
    return __uint_as_float(((uint)h) << 16);
}

// ---------------------------------------------------------------------------
// Kernel 1: input projection GEMM via bf16x3 split MFMA.
// NEW GRID: one block per (direction, m-tile) = (2, 500) — each block
// computes ALL 256 columns of one direction. x-tile read 2x total (vs 4x),
// W streamed once per block: cuts redundant L2/L3/HBM traffic ~2x.
// Arithmetic identical per output element (same k order, same hh/hl/lh MFMA
// sequence) -> bit-identical P vs R6/R9/R13.
// 4 waves as 2x2 over (row-half 64, col-half 128): 4 fr x 8 fc frags/wave,
// acc = 128 VGPR. LDS: A 20KB + B 40KB = 60KB -> 2 blocks/CU.
// ---------------------------------------------------------------------------
__global__ __launch_bounds__(256) void proj_mfma(
    const float* __restrict__ x,
    const float* __restrict__ Wf, const float* __restrict__ Wb,
    const float* __restrict__ biasf, const float* __restrict__ biasb,
    float* __restrict__ P)
{
    __shared__ ushort AsH[128][40];
    __shared__ ushort AsL[128][40];
    __shared__ ushort BsH[256][40];
    __shared__ ushort BsL[256][40];

    const int nt = blockIdx.x;          // 0 = fw cols, 1 = bw cols
    const int mt = blockIdx.y;          // 0..499
    const int m0 = mt * 128;
    const float* W   = nt ? Wb : Wf;
    const float* bia = nt ? biasb : biasf;

    const int tid  = threadIdx.x;
    const int lane = tid & 63;
    const int wv   = tid >> 6;          // wave 0..3
    const int wr   = wv >> 1;           // row-half
    const int wc   = wv & 1;            // col-half (128 cols each)
    const int l15  = lane & 15;
    const int l4   = lane >> 4;

    const int as  = tid & 7;            // A k-slot (4 floats)
    const int arr = tid >> 3;           // A row 0..31 (x4 row-groups)

    f32x4 acc[4][8];
#pragma unroll
    for (int i = 0; i < 4; i++)
#pragma unroll
        for (int j = 0; j < 8; j++)
            acc[i][j] = (f32x4){0.f, 0.f, 0.f, 0.f};

    float4 av[4];
    float bv[32];

#define PROJ_LOAD(K0_) do {                                                   \
        const int ka_ = (K0_) + as * 4;                                       \
        const bool aok_ = (ka_ + 3) < CIN;                                    \
        _Pragma("unroll")                                                     \
        for (int i_ = 0; i_ < 4; i_++) {                                      \
            av[i_] = make_float4(0.f, 0.f, 0.f, 0.f);                         \
            if (aok_)                                                         \
                av[i_] = *(const float4*)&x[(size_t)(m0 + arr + 32 * i_) * CIN + ka_]; \
        }                                                                     \
        _Pragma("unroll")                                                     \
        for (int j_ = 0; j_ < 32; j_++) {                                     \
            const int kb_ = (K0_) + j_;                                       \
            bv[j_] = (kb_ < CIN) ? W[(size_t)kb_ * HID + tid] : 0.f;          \
        }                                                                     \
    } while (0)

#define PROJ_CVT_WRITE() do {                                                 \
        _Pragma("unroll")                                                     \
        for (int i_ = 0; i_ < 4; i_++) {                                      \
            const int row_ = arr + 32 * i_;                                   \
            ushort4 h_, l_;                                                   \
            h_.x = f2bf_rne(av[i_].x); l_.x = f2bf_rne(__fsub_rn(av[i_].x, bf2f(h_.x))); \
            h_.y = f2bf_rne(av[i_].y); l_.y = f2bf_rne(__fsub_rn(av[i_].y, bf2f(h_.y))); \
            h_.z = f2bf_rne(av[i_].z); l_.z = f2bf_rne(__fsub_rn(av[i_].z, bf2f(h_.z))); \
            h_.w = f2bf_rne(av[i_].w); l_.w = f2bf_rne(__fsub_rn(av[i_].w, bf2f(h_.w))); \
            *(ushort4*)&AsH[row_][as * 4] = h_;                               \
            *(ushort4*)&AsL[row_][as * 4] = l_;                               \
        }                                                                     \
        _Pragma("unroll")                                                     \
        for (int q_ = 0; q_ < 8; q_++) {                                      \
            ushort4 h_, l_;                                                   \
            float v0_ = bv[q_ * 4 + 0], v1_ = bv[q_ * 4 + 1];                 \
            float v2_ = bv[q_ * 4 + 2], v3_ = bv[q_ * 4 + 3];                 \
            h_.x = f2bf_rne(v0_); l_.x = f2bf_rne(__fsub_rn(v0_, bf2f(h_.x))); \
            h_.y = f2bf_rne(v1_); l_.y = f2bf_rne(__fsub_rn(v1_, bf2f(h_.y))); \
            h_.z = f2bf_rne(v2_); l_.z = f2bf_rne(__fsub_rn(v2_, bf2f(h_.z))); \
            h_.w = f2bf_rne(v3_); l_.w = f2bf_rne(__fsub_rn(v3_, bf2f(h_.w))); \
            *(ushort4*)&BsH[tid][q_ * 4] = h_;                               \
            *(ushort4*)&BsL[tid][q_ * 4] = l_;                               \
        }                                                                     \
    } while (0)

    PROJ_LOAD(0);
    PROJ_CVT_WRITE();

    for (int kt = 0; kt < KSTEPS; kt++) {
        __syncthreads();                 // tile kt writes visible
        if (kt + 1 < KSTEPS)
            PROJ_LOAD((kt + 1) * 32);    // next loads land during MFMA

#pragma unroll
        for (int fc = 0; fc < 8; fc++) {
            const bf16x8 bHf = *(const bf16x8*)&BsH[wc * 128 + fc * 16 + l15][l4 * 8];
            const bf16x8 bLf = *(const bf16x8*)&BsL[wc * 128 + fc * 16 + l15][l4 * 8];
#pragma unroll
            for (int fr = 0; fr < 4; fr++) {
                const bf16x8 aHf = *(const bf16x8*)&AsH[wr * 64 + fr * 16 + l15][l4 * 8];
                const bf16x8 aLf = *(const bf16x8*)&AsL[wr * 64 + fr * 16 + l15][l4 * 8];
                acc[fr][fc] = __builtin_amdgcn_mfma_f32_16x16x32_bf16(
                    aHf, bHf, acc[fr][fc], 0, 0, 0);
                acc[fr][fc] = __builtin_amdgcn_mfma_f32_16x16x32_bf16(
                    aHf, bLf, acc[fr][fc], 0, 0, 0);
                acc[fr][fc] = __builtin_amdgcn_mfma_f32_16x16x32_bf16(
                    aLf, bHf, acc[fr][fc], 0, 0, 0);
            }
        }

        __syncthreads();                 // all reads of tile kt done
        if (kt + 1 < KSTEPS)
            PROJ_CVT_WRITE();
    }

#undef PROJ_LOAD
#undef PROJ_CVT_WRITE

#pragma unroll
    for (int fc = 0; fc < 8; fc++) {
        const int col = wc * 128 + fc * 16 + l15;      // 0..255 in direction
        const float bvs = bia[col];
#pragma unroll
        for (int fr = 0; fr < 4; fr++) {
#pragma unroll
            for (int j = 0; j < 4; j++) {
                const int row = m0 + wr * 64 + fr * 16 + l4 * 4 + j;
                P[(size_t)row * 512 + nt * HID + col] =
                    __fadd_rn(acc[fr][fc][j], bvs);
            }
        }
    }
}

// ---------------------------------------------------------------------------
// Kernel 2: MFMA scan — EXACT R6 form (best measured: 294us, absmax 0.0625).
// R9/R10/R13 variants (pv timing, acc split, delayed readout) all measured
// neutral-or-worse; reverted.
// ---------------------------------------------------------------------------
__global__ __launch_bounds__(512, 2) void scan_mfma(
    const float* __restrict__ P,
    const float* __restrict__ Wrecf, const float* __restrict__ brecf,
    const float* __restrict__ taumf, const float* __restrict__ tauaf,
    const float* __restrict__ Wrecb, const float* __restrict__ brecb,
    const float* __restrict__ taumb, const float* __restrict__ tauab,
    const float* __restrict__ Wout, const float* __restrict__ taumo,
    float* __restrict__ Pst)
{
    const int g  = blockIdx.x;          // batch group: b0..b0+15
    const int d  = blockIdx.y;          // 0 = fw, 1 = bw
    const int b0 = g * 16;
    const bool fw = (d == 0);

    const int tid  = threadIdx.x;
    const int lane = tid & 63;
    const int w    = tid >> 6;          // wave 0..7
    const int l15  = lane & 15;
    const int l4   = lane >> 4;

    __shared__ ushort Sp[2][16][264];   // [buf][batch][col(+pad)] bf16 spikes

    {   // zero both spike buffers (step -1 spikes = 0)
        ushort* p = &Sp[0][0][0];
        for (int i = tid; i < 2 * 16 * 264; i += 512) p[i] = 0;
    }

    const float* Wrec = fw ? Wrecf : Wrecb;

    // ---- W_rec fragments (hi+lo bf16), register resident
    bf16x8 whf[8][2], wlf[8][2];
#pragma unroll
    for (int kt = 0; kt < 8; kt++)
#pragma unroll
        for (int ct = 0; ct < 2; ct++) {
            const int c = w * 32 + ct * 16 + l15;
#pragma unroll
            for (int j = 0; j < 8; j++) {
                const float v = Wrec[(size_t)(kt * 32 + l4 * 8 + j) * HID + c];
                const ushort h = f2bf_rne(v);
                const ushort l = f2bf_rne(__fsub_rn(v, bf2f(h)));
                whf[kt][ct][j] = (short)h;
                wlf[kt][ct][j] = (short)l;
            }
        }

    // ---- W_out fragments for this wave's 32-k slice (hi+lo)
    bf16x8 woh[2], wol[2];
#pragma unroll
    for (int t = 0; t < 2; t++) {
        const int o = t * 16 + l15;
#pragma unroll
        for (int j = 0; j < 8; j++) {
            float v = 0.f;
            if (o < OUT_N)
                v = Wout[(size_t)(d * HID + w * 32 + l4 * 8 + j) * OUT_N + o];
            const ushort h = f2bf_rne(v);
            const ushort l = f2bf_rne(__fsub_rn(v, bf2f(h)));
            woh[t][j] = (short)h;
            wol[t][j] = (short)l;
        }
    }

    // ---- LIF constants for this thread's 2 columns
    float alpha_[2], ro_[2], omA_[2], omR_[2], brc_[2];
#pragma unroll
    for (int t = 0; t < 2; t++) {
        const int c = w * 32 + t * 16 + l15;
        alpha_[t] = expf(__fdiv_rn(-1.f, fw ? taumf[c] : taumb[c]));
        ro_[t]    = expf(__fdiv_rn(-1.f, fw ? tauaf[c] : tauab[c]));
        omA_[t]   = __fsub_rn(1.f, alpha_[t]);
        omR_[t]   = __fsub_rn(1.f, ro_[t]);
        brc_[t]   = fw ? brecf[c] : brecb[c];
    }
    // ---- readout constants
    float ao_[2], omo_[2];
#pragma unroll
    for (int t = 0; t < 2; t++) {
        const int o = t * 16 + l15;
        if (o < OUT_N) {
            ao_[t]  = expf(__fdiv_rn(-1.f, taumo[o]));
            omo_[t] = __fsub_rn(1.f, ao_[t]);
        } else { ao_[t] = 0.f; omo_[t] = 0.f; }
    }

    float mem[2][4], bbv[2][4], spkv[2][4], z[2][4];
#pragma unroll
    for (int t = 0; t < 2; t++)
#pragma unroll
        for (int j = 0; j < 4; j++) {
            mem[t][j] = 0.f; bbv[t][j] = 0.01f; spkv[t][j] = 0.f; z[t][j] = 0.f;
        }

    // pv prefetch for s=0
    float pv[2][4];
    {
        const int srow = fw ? 0 : (S_LEN - 1);
#pragma unroll
        for (int t = 0; t < 2; t++)
#pragma unroll
            for (int j = 0; j < 4; j++)
                pv[t][j] = P[((size_t)(b0 + l4 * 4 + j) * S_LEN + srow) * 512
                             + d * HID + w * 32 + t * 16 + l15];
    }

    for (int s = 0; s < S_LEN; s++) {
        const int cur = s & 1, prev = cur ^ 1;

        // prefetch next step's projection BEFORE the barrier (R6 exact)
        float pv_next[2][4];
        {
            const int sn   = (s + 1 < S_LEN) ? s + 1 : S_LEN - 1;
            const int srow = fw ? sn : (S_LEN - 1 - sn);
#pragma unroll
            for (int t = 0; t < 2; t++)
#pragma unroll
                for (int j = 0; j < 4; j++)
                    pv_next[t][j] = P[((size_t)(b0 + l4 * 4 + j) * S_LEN + srow) * 512
                                      + d * HID + w * 32 + t * 16 + l15];
        }

        __syncthreads();   // Sp[prev] complete from all waves

        // ---- recurrent GEMM: D[batch][col] += spk(prev) @ W_rec
        f32x4 acc[2];
        acc[0] = (f32x4){0.f, 0.f, 0.f, 0.f};
        acc[1] = (f32x4){0.f, 0.f, 0.f, 0.f};
#pragma unroll
        for (int kt = 0; kt < 8; kt++) {
            const bf16x8 a = *(const bf16x8*)&Sp[prev][l15][kt * 32 + l4 * 8];
            acc[0] = __builtin_amdgcn_mfma_f32_16x16x32_bf16(a, whf[kt][0], acc[0], 0, 0, 0);
            acc[0] = __builtin_amdgcn_mfma_f32_16x16x32_bf16(a, wlf[kt][0], acc[0], 0, 0, 0);
            acc[1] = __builtin_amdgcn_mfma_f32_16x16x32_bf16(a, whf[kt][1], acc[1], 0, 0, 0);
            acc[1] = __builtin_amdgcn_mfma_f32_16x16x32_bf16(a, wlf[kt][1], acc[1], 0, 0, 0);
        }

        // ---- adaptive-LIF update on the C/D fragment (exact ref rounding)
#pragma unroll
        for (int t = 0; t < 2; t++) {
#pragma unroll
            for (int j = 0; j < 4; j++) {
                const float dd = __fadd_rn(__fadd_rn(pv[t][j], acc[t][j]), brc_[t]);
                bbv[t][j] = __fadd_rn(__fmul_rn(ro_[t], bbv[t][j]),
                                      __fmul_rn(omR_[t], spkv[t][j]));
                const float thr = __fadd_rn(0.01f, __fmul_rn(1.8f, bbv[t][j]));
                mem[t][j] = __fsub_rn(
                    __fadd_rn(__fmul_rn(mem[t][j], alpha_[t]),
                              __fmul_rn(omA_[t], dd)),
                    __fmul_rn(thr, spkv[t][j]));
                const bool sp = __fsub_rn(mem[t][j], thr) > 0.f;
                spkv[t][j] = sp ? 1.f : 0.f;
                Sp[cur][l4 * 4 + j][w * 32 + t * 16 + l15] =
                    sp ? (ushort)0x3F80 : (ushort)0;
            }
        }

        // make own-wave spike writes visible to own-wave cross-lane reads
        asm volatile("s_waitcnt lgkmcnt(0)" ::: "memory");
        __builtin_amdgcn_sched_barrier(0);

        // ---- readout partial: this wave's 32-col k-slice of spk(cur)
        {
            const bf16x8 ar = *(const bf16x8*)&Sp[cur][l15][w * 32 + l4 * 8];
            f32x4 S0 = (f32x4){0.f, 0.f, 0.f, 0.f};
            f32x4 S1 = (f32x4){0.f, 0.f, 0.f, 0.f};
            S0 = __builtin_amdgcn_mfma_f32_16x16x32_bf16(ar, woh[0], S0, 0, 0, 0);
            S0 = __builtin_amdgcn_mfma_f32_16x16x32_bf16(ar, wol[0], S0, 0, 0, 0);
            S1 = __builtin_amdgcn_mfma_f32_16x16x32_bf16(ar, woh[1], S1, 0, 0, 0);
            S1 = __builtin_amdgcn_mfma_f32_16x16x32_bf16(ar, wol[1], S1, 0, 0, 0);
#pragma unroll
            for (int j = 0; j < 4; j++) {
                z[0][j] = __fmaf_rn(ao_[0], z[0][j], __fmul_rn(omo_[0], S0[j]));
                z[1][j] = __fmaf_rn(ao_[1], z[1][j], __fmul_rn(omo_[1], S1[j]));
            }
        }

#pragma unroll
        for (int t = 0; t < 2; t++)
#pragma unroll
            for (int j = 0; j < 4; j++) pv[t][j] = pv_next[t][j];
    }

    __syncthreads();   // all waves done reading P rows we now overwrite

    // ---- stash per-wave readout partials into consumed P rows
    float* stash = Pst + ((size_t)b0 * S_LEN) * 512 + d * HID;
#pragma unroll
    for (int j = 0; j < 4; j++) {
        const int r = l4 * 4 + j;
        const int idx0 = w * 320 + r * 16 + l15;
        stash[(size_t)(idx0 >> 8) * 512 + (idx0 & 255)] = z[0][j];
        if (l15 < 4) {
            const int idx1 = w * 320 + 256 + r * 4 + l15;
            stash[(size_t)(idx1 >> 8) * 512 + (idx1 & 255)] = z[1][j];
        }
    }
}

// ---------------------------------------------------------------------------
// Kernel 3: merge stashed partials + bias closed form + log_softmax.
// ---------------------------------------------------------------------------
__global__ __launch_bounds__(64) void merge_out(
    const float* __restrict__ Pst, const float* __restrict__ bout,
    const float* __restrict__ taumo, float* __restrict__ out)
{
    const int bb = blockIdx.x;
    const int o  = threadIdx.x;         // active 0..19
    const int g  = bb >> 4, r = bb & 15;

    float val = 0.f, v = -3.0e38f;
    if (o < OUT_N) {
        float tot = 0.f;
#pragma unroll
        for (int d2 = 0; d2 < 2; d2++) {
            const float* stash = Pst + ((size_t)(g * 16) * S_LEN) * 512 + d2 * HID;
#pragma unroll
            for (int w2 = 0; w2 < 8; w2++) {
                const int idx = (o < 16) ? (w2 * 320 + r * 16 + o)
                                         : (w2 * 320 + 256 + r * 4 + (o - 16));
                tot = __fadd_rn(tot, stash[(size_t)(idx >> 8) * 512 + (idx & 255)]);
            }
        }
        const float aS = expf(__fdiv_rn(-(float)S_LEN, taumo[o]));
        val = __fadd_rn(tot, __fmul_rn(bout[o], __fsub_rn(1.f, aS)));
        v = val;
    }
    float mx = v;
#pragma unroll
    for (int d2 = 1; d2 < 64; d2 <<= 1)
        mx = fmaxf(mx, __shfl_xor(mx, d2, 64));
    float e = (o < OUT_N) ? expf(__fsub_rn(val, mx)) : 0.f;
#pragma unroll
    for (int d2 = 1; d2 < 64; d2 <<= 1)
        e += __shfl_xor(e, d2, 64);
    if (o < OUT_N)
        out[(size_t)bb * OUT_N + o] =
            __fsub_rn(__fsub_rn(val, mx), logf(e));
}

// ---------------------------------------------------------------------------
extern "C" void kernel_launch(void* const* d_in, const int* in_sizes, int n_in,
                              void* d_out, int out_size, void* d_ws, size_t ws_size,
                              hipStream_t stream) {
    const float* x         = (const float*)d_in[0];
    const float* W_in_f    = (const float*)d_in[1];
    const float* b_in_f    = (const float*)d_in[2];
    const float* W_rec_f   = (const float*)d_in[3];
    const float* b_rec_f   = (const float*)d_in[4];
    const float* tau_m_f   = (const float*)d_in[5];
    const float* tau_adp_f = (const float*)d_in[6];
    const float* W_in_b    = (const float*)d_in[7];
    const float* b_in_b    = (const float*)d_in[8];
    const float* W_rec_b   = (const float*)d_in[9];
    const float* b_rec_b   = (const float*)d_in[10];
    const float* W_out     = (const float*)d_in[13];
    const float* b_out     = (const float*)d_in[14];
    const float* tau_m_o   = (const float*)d_in[15];
    const float* tau_m_b   = (const float*)d_in[11];
    const float* tau_adp_b = (const float*)d_in[12];
    float* out = (float*)d_out;
    float* P   = (float*)d_ws;

    proj_mfma<<<dim3(2, 500), dim3(256), 0, stream>>>(
        x, W_in_f, W_in_b, b_in_f, b_in_b, P);
    scan_mfma<<<dim3(16, 2), dim3(512), 0, stream>>>(
        P, W_rec_f, b_rec_f, tau_m_f, tau_adp_f,
        W_rec_b, b_rec_b, tau_m_b, tau_adp_b,
        W_out, tau_m_o, P);
    merge_out<<<dim3(BATCH), dim3(64), 0, stream>>>(
        P, b_out, tau_m_o, out);
}